// Round 6
// baseline (80.791 us; speedup 1.0000x reference)
//
#include <hip/hip_runtime.h>

#define M_NODES 100000
#define BM 32
#define NT (M_NODES / BM)               // 3125 tiles, exact (no tail)
#define GRID 512                         // 2 blocks/CU, persistent

typedef float  f32x4  __attribute__((ext_vector_type(4)));
typedef short  bf16x8 __attribute__((ext_vector_type(8)));

__device__ __forceinline__ unsigned short f2bf(float f) {
  union { float f; unsigned int u; } v; v.f = f;
  unsigned int u = v.u;
  return (unsigned short)((u + 0x7FFFu + ((u >> 16) & 1u)) >> 16);  // RNE
}

__device__ __forceinline__ bf16x8 cvt8(f32x4 u0, f32x4 u1) {
  union { unsigned int u[4]; bf16x8 v; } r;
  asm("v_cvt_pk_bf16_f32 %0, %1, %2" : "=v"(r.u[0]) : "v"(u0[0]), "v"(u0[1]));
  asm("v_cvt_pk_bf16_f32 %0, %1, %2" : "=v"(r.u[1]) : "v"(u0[2]), "v"(u0[3]));
  asm("v_cvt_pk_bf16_f32 %0, %1, %2" : "=v"(r.u[2]) : "v"(u1[0]), "v"(u1[1]));
  asm("v_cvt_pk_bf16_f32 %0, %1, %2" : "=v"(r.u[3]) : "v"(u1[2]), "v"(u1[3]));
  return r.v;
}

// lgkm-only barrier: global prefetch stays in flight across it (no vmcnt drain)
#define BARRIER() do { asm volatile("s_waitcnt lgkmcnt(0)" ::: "memory"); \
                       __builtin_amdgcn_s_barrier();                       \
                       __builtin_amdgcn_sched_barrier(0); } while (0)

// ---------------------------------------------------------------------------
// prep: W[k][n] f32 -> frag-major bf16 image. Fragment (g,kk) = cols
// g*16..+16, k kk*32..+32; stored as 64 lanes x 16B contiguous (1 KB/frag):
//   img[((g*8+kk)*64 + lane)*8 + j] = bf16( W[kk*32+(lane>>4)*8+j][g*16+(lane&15)] )
// One coalesced 1KB load per B-fragment in the GEMM (all L2-resident).
// ---------------------------------------------------------------------------
__global__ void prep_w(const float* __restrict__ W1, const float* __restrict__ W2,
                       unsigned short* __restrict__ F1, unsigned short* __restrict__ F2) {
  int b = blockIdx.x;                   // 256 blocks x 64 threads
  const float* W = (b < 128) ? W1 : W2;
  unsigned short* F = (b < 128) ? F1 : F2;
  int g  = (b & 127) >> 3;              // 0..15 col-group
  int kk = b & 7;                       // 0..7  k-step
  int lane = threadIdx.x;
  int n  = g * 16 + (lane & 15);
  int k0 = kk * 32 + (lane >> 4) * 8;
  union { unsigned short h[8]; bf16x8 v; } r;
  #pragma unroll
  for (int j = 0; j < 8; ++j) r.h[j] = f2bf(W[(k0 + j) * 256 + n]);
  *(bf16x8*)(F + (size_t)(((g * 8 + kk) * 64 + lane)) * 8) = r.v;
}

// ---------------------------------------------------------------------------
// Persistent fused kernel: per 32-row tile, out = relu(X@W1+b1)@W2 + b2.
// 512 blocks x 256 thr (4 waves); wave w owns output cols [64w, 64w+64).
// A (GEMM1): f32 from LDS Xbuf (XOR-swizzled via pre-swizzled global src,
//            linear global_load_lds dest), cvt_pk at frag load.
// A (GEMM2): bf16 from Hbuf (R2-proven 3-bit slot swizzle).
// B (both):  1KB coalesced frag loads from L2-resident frag-major W images.
// Sync per tile: 2 lgkm barriers + ONE vmcnt(0) (after GEMM2 has covered the
// X(t+1) stage latency). Stores issued after the barrier, drained next tile.
// LDS 80 KB (X dbuf 2x32K + H 16K) -> 2 blocks/CU.
// ---------------------------------------------------------------------------
__global__ __launch_bounds__(256, 2)
void cheb_fused(const float* __restrict__ X,
                const unsigned short* __restrict__ Wf1,
                const unsigned short* __restrict__ Wf2,
                const float* __restrict__ b1,
                const float* __restrict__ b2,
                float* __restrict__ out)
{
  __shared__ float          Xb[2][BM * 256];   // 2 x 32 KB
  __shared__ unsigned short Hbuf[BM * 256];    // 16 KB

  const int tid  = threadIdx.x;
  const int lane = tid & 63;
  const int l15  = lane & 15;
  const int lhi  = lane >> 4;                  // 0..3
  const int w    = tid >> 6;                   // 0..3 (col quarter)

  // stage one 32x256 f32 tile; lane l writes phys slot l of row r (linear
  // dest), so it fetches logical slot l^(r&7) from global (inverse swizzle).
  auto stage = [&](int t, float* buf) {
    #pragma unroll
    for (int i = 0; i < 8; ++i) {
      int r = w * 8 + i;
      const float* src = X + (size_t)(t * BM + r) * 256 + ((lane ^ (r & 7)) << 2);
      __builtin_amdgcn_global_load_lds(
          (const __attribute__((address_space(1))) unsigned int*)(const void*)src,
          (__attribute__((address_space(3))) unsigned int*)(void*)(buf + r * 256),
          16, 0, 0);
    }
  };

  auto g1 = [&](const float* Xc, f32x4 (&acc)[2][4]) {
    #pragma unroll
    for (int kk = 0; kk < 8; ++kk) {
      bf16x8 b[4];
      #pragma unroll
      for (int ni = 0; ni < 4; ++ni)
        b[ni] = *(const bf16x8*)(Wf1 + (size_t)(((w * 4 + ni) * 8 + kk) * 64 + lane) * 8);
      bf16x8 a[2];
      #pragma unroll
      for (int mi = 0; mi < 2; ++mi) {
        int r = mi * 16 + l15;
        int s = kk * 8 + lhi * 2;              // 16B slot index (4 f32)
        f32x4 v0 = *(const f32x4*)(Xc + r * 256 + ((s       ^ (r & 7)) << 2));
        f32x4 v1 = *(const f32x4*)(Xc + r * 256 + (((s + 1) ^ (r & 7)) << 2));
        a[mi] = cvt8(v0, v1);
      }
      #pragma unroll
      for (int mi = 0; mi < 2; ++mi)
        #pragma unroll
        for (int ni = 0; ni < 4; ++ni)
          acc[mi][ni] = __builtin_amdgcn_mfma_f32_16x16x32_bf16(a[mi], b[ni], acc[mi][ni], 0, 0, 0);
    }
  };

  auto g2 = [&](f32x4 (&acc)[2][4]) {
    #pragma unroll
    for (int kk = 0; kk < 8; ++kk) {
      bf16x8 b[4];
      #pragma unroll
      for (int ni = 0; ni < 4; ++ni)
        b[ni] = *(const bf16x8*)(Wf2 + (size_t)(((w * 4 + ni) * 8 + kk) * 64 + lane) * 8);
      bf16x8 a[2];
      #pragma unroll
      for (int mi = 0; mi < 2; ++mi) {
        int r = mi * 16 + l15;
        int ks = (kk * 4 + lhi) ^ (r & 7);
        a[mi] = *(const bf16x8*)(Hbuf + r * 256 + (ks << 3));
      }
      #pragma unroll
      for (int mi = 0; mi < 2; ++mi)
        #pragma unroll
        for (int ni = 0; ni < 4; ++ni)
          acc[mi][ni] = __builtin_amdgcn_mfma_f32_16x16x32_bf16(a[mi], b[ni], acc[mi][ni], 0, 0, 0);
    }
  };

  float bn1[4], bn2[4];
  #pragma unroll
  for (int ni = 0; ni < 4; ++ni) {
    bn1[ni] = b1[w * 64 + ni * 16 + l15];
    bn2[ni] = b2[w * 64 + ni * 16 + l15];
  }

  // ---- prologue: stage first tile ----------------------------------------
  const int t0 = blockIdx.x;
  stage(t0, Xb[0]);
  asm volatile("s_waitcnt vmcnt(0)" ::: "memory");
  BARRIER();

  int it = 0;
  for (int t = t0; t < NT; t += GRID, ++it) {
    float* Xc = Xb[it & 1];
    float* Xn = Xb[(it + 1) & 1];

    // GEMM1
    f32x4 acc[2][4] = {};
    g1(Xc, acc);

    // epilogue1: bias + relu + bf16 -> Hbuf (3-bit slot swizzle)
    #pragma unroll
    for (int ni = 0; ni < 4; ++ni) {
      int k = w * 64 + ni * 16 + l15;
      #pragma unroll
      for (int mi = 0; mi < 2; ++mi)
        #pragma unroll
        for (int rg = 0; rg < 4; ++rg) {
          int r = mi * 16 + lhi * 4 + rg;
          float v = fmaxf(acc[mi][ni][rg] + bn1[ni], 0.f);
          Hbuf[r * 256 + (((k >> 3) ^ (r & 7)) << 3) + (k & 7)] = f2bf(v);
        }
    }
    BARRIER();                               // Hbuf ready; Xc reads drained

    // issue next-tile X stage (in flight under GEMM2)
    if (t + GRID < NT) stage(t + GRID, Xn);

    // GEMM2
    f32x4 acc2[2][4] = {};
    g2(acc2);

    // drain X(t+1) stage (covered by GEMM2) before crossing into next tile
    asm volatile("s_waitcnt vmcnt(0)" ::: "memory");
    __builtin_amdgcn_sched_barrier(0);
    BARRIER();

    // epilogue2: stores overlap next tile's GEMM1
    #pragma unroll
    for (int mi = 0; mi < 2; ++mi)
      #pragma unroll
      for (int rg = 0; rg < 4; ++rg) {
        int grow = t * BM + mi * 16 + lhi * 4 + rg;
        #pragma unroll
        for (int ni = 0; ni < 4; ++ni)
          __builtin_nontemporal_store(acc2[mi][ni][rg] + bn2[ni],
                                      out + (size_t)grow * 256 + w * 64 + ni * 16 + l15);
      }
  }
}

// ---------------------------------------------------------------------------
extern "C" void kernel_launch(void* const* d_in, const int* in_sizes, int n_in,
                              void* d_out, int out_size, void* d_ws, size_t ws_size,
                              hipStream_t stream) {
  const float* emb = (const float*)d_in[0];
  const float* W1  = (const float*)d_in[1];
  const float* b1  = (const float*)d_in[2];
  const float* W2  = (const float*)d_in[3];
  const float* b2  = (const float*)d_in[4];
  // d_in[5] = prop_edge_index: unused at ChebConv K=1.
  float* out = (float*)d_out;

  unsigned short* F1 = (unsigned short*)d_ws;   // 65536 ushorts (128KB)
  unsigned short* F2 = F1 + 65536;              // 128KB

  prep_w<<<256, 64, 0, stream>>>(W1, W2, F1, F2);
  cheb_fused<<<GRID, 256, 0, stream>>>(emb, F1, F2, b1, b2, out);
}